// Round 20
// baseline (141.728 us; speedup 1.0000x reference)
//
#include <hip/hip_runtime.h>
#include <math.h>
#include <stdint.h>

// EMACE forward. R20 = R19 +
//  - gather_node_k: 8-edge guarded load batches (one latency round for most
//    nodes, deg~4.5), launch_bounds(512,2) for the larger live set.
//  - pack_w_k merged into clear_k (one fewer dispatch).
// Everything else unchanged from R19 (118.6 us).

#define PI_F 3.14159265358979323846f
#define ECAP_MAX 72000       // active-edge capacity (expected ~46k)
#define WPK_PER_LAYER 24576  // 4096 (W2f) + 4096 (W3f) + 16384 (W4f)

__device__ __forceinline__ float silu_f(float x) { return x / (1.f + __expf(-x)); }

__device__ __forceinline__ unsigned short f2bf(float f) {
  unsigned int u = __float_as_uint(f);
  u = (u + 0x7FFFu + ((u >> 16) & 1u)) >> 16;  // round-to-nearest-even
  return (unsigned short)u;
}
__device__ __forceinline__ float bf2f(unsigned short h) {
  return __uint_as_float(((unsigned int)h) << 16);
}

typedef __attribute__((ext_vector_type(8))) short short8v;  // 8 bf16
typedef __attribute__((ext_vector_type(4))) float floatx4;  // 4 f32 acc

#define LDSFENCE() asm volatile("s_waitcnt lgkmcnt(0)" ::: "memory")

// B-fragment index for a [64k x NC] weight element (k, c) (HW-verified R17/18)
__device__ __forceinline__ int bfrag_idx(int k, int c) {
  return ((((c >> 4) * 2 + (k >> 5)) * 64) + (((k >> 3) & 3) * 16 + (c & 15))) * 8 +
         (k & 7);
}

// ------------------------------------------------- clear + weight pre-pack
__global__ void clear_pack_k(int* __restrict__ deg, int* __restrict__ cur,
                             int N, const float* __restrict__ Wr2,
                             const float* __restrict__ Wr3,
                             const float* __restrict__ Wr4,
                             unsigned short* __restrict__ Wpack, int nlayer,
                             int nclr) {
  int bid = blockIdx.x;
  if (bid < nclr) {
    int i = bid * 256 + threadIdx.x;
    if (i < N) {
      deg[i] = 0;
      cur[i] = 0;
    }
    return;
  }
  int i = (bid - nclr) * 256 + threadIdx.x;
  int total = nlayer * WPK_PER_LAYER;
  if (i >= total) return;
  int layer = i / WPK_PER_LAYER, r = i % WPK_PER_LAYER;
  unsigned short* dst = Wpack + (size_t)layer * WPK_PER_LAYER;
  if (r < 4096) {
    int k = r >> 6, c = r & 63;
    dst[bfrag_idx(k, c)] = f2bf(Wr2[(size_t)layer * 4096 + r]);
  } else if (r < 8192) {
    int q = r - 4096;
    int k = q >> 6, c = q & 63;
    dst[4096 + bfrag_idx(k, c)] = f2bf(Wr3[(size_t)layer * 4096 + q]);
  } else {
    int q = r - 8192;
    int k = q >> 8, c = q & 255;
    dst[8192 + (c >> 7) * 8192 + bfrag_idx(k, c & 127)] =
        f2bf(Wr4[(size_t)layer * 16384 + q]);
  }
}

// --------------------------------------------------- node init + edge count
__global__ void prep_k(const float* __restrict__ attrs,
                       const float* __restrict__ ae,
                       const float* __restrict__ Wemb, float* __restrict__ h0,
                       int* __restrict__ spec, float* __restrict__ node_e0,
                       int N, int NE, const float* __restrict__ pos,
                       const float* __restrict__ shifts,
                       const int* __restrict__ ei, int* __restrict__ deg,
                       int E, int nblk) {
  int bid = blockIdx.x;
  if (bid < nblk) {
    int n = bid * 4 + ((int)threadIdx.x >> 6);
    int lane = threadIdx.x & 63;
    if (n >= N) return;
    const float* a = attrs + (size_t)n * NE;
    int sp = 0;
    for (int e = 0; e < NE; ++e)
      if (a[e] > 0.5f) sp = e;
    h0[(size_t)n * 64 + lane] = Wemb[sp * 64 + lane];
    if (lane == 0) {
      spec[n] = sp;
      node_e0[n] = ae[sp];
    }
  } else {
    int e = (bid - nblk) * 256 + threadIdx.x;
    if (e >= E) return;
    int s = ei[e], r = ei[E + e];
    float dx = pos[r * 3 + 0] - pos[s * 3 + 0] + shifts[e * 3 + 0];
    float dy = pos[r * 3 + 1] - pos[s * 3 + 1] + shifts[e * 3 + 1];
    float dz = pos[r * 3 + 2] - pos[s * 3 + 2] + shifts[e * 3 + 2];
    float d2 = dx * dx + dy * dy + dz * dz;
    if (d2 < 25.0f) atomicAdd(&deg[r], 1);
  }
}

// ---------------------------------------------------------------- scan
__global__ void scan_deg_k(const int* __restrict__ deg, int* __restrict__ off,
                           int N) {
  __shared__ int sdat[1024];
  int tid = threadIdx.x;
  int chunk = (N + 1023) / 1024;
  int s0 = tid * chunk, s1 = min(s0 + chunk, N);
  int s = 0;
  for (int i = s0; i < s1; ++i) s += deg[i];
  sdat[tid] = s;
  __syncthreads();
  for (int d = 1; d < 1024; d <<= 1) {
    int v = (tid >= d) ? sdat[tid - d] : 0;
    __syncthreads();
    sdat[tid] += v;
    __syncthreads();
  }
  int run = sdat[tid] - s;  // exclusive prefix
  for (int i = s0; i < s1; ++i) {
    off[i] = run;
    run += deg[i];
  }
  if (tid == 1023) off[N] = sdat[1023];
}

// ---------------------------------------------------------------- edge pass 2
__global__ void edge_fill_k(const float* __restrict__ pos,
                            const float* __restrict__ shifts,
                            const int* __restrict__ ei,
                            const int* __restrict__ off, int* __restrict__ cur,
                            int* __restrict__ send, float* __restrict__ Yc,
                            float* __restrict__ fc, int E, int ecap) {
  int e = blockIdx.x * blockDim.x + threadIdx.x;
  if (e >= E) return;
  int s = ei[e], r = ei[E + e];
  float dx = pos[r * 3 + 0] - pos[s * 3 + 0] + shifts[e * 3 + 0];
  float dy = pos[r * 3 + 1] - pos[s * 3 + 1] + shifts[e * 3 + 1];
  float dz = pos[r * 3 + 2] - pos[s * 3 + 2] + shifts[e * 3 + 2];
  float rr = sqrtf(dx * dx + dy * dy + dz * dz + 1e-12f);
  if (rr >= 5.0f) return;  // inactive edge: cutoff=0 -> R=0 -> msg=0
  int p = off[r] + atomicAdd(&cur[r], 1);
  if (p >= ecap) return;  // statistically impossible; memory-safety guard
  send[p] = s;
  float ir = 1.f / rr;
  float x = dx * ir, y = dy * ir, z = dz * ir;
  const float s3 = 1.73205080757f, s5 = 2.23606797750f, s15 = 3.87298334621f;
  const float c70 = 2.09165006634f;   // sqrt(70)/4
  const float c105 = 10.2469507660f;  // sqrt(105)
  const float c42 = 1.62018517460f;   // sqrt(42)/4
  const float c7 = 1.32287565553f;    // sqrt(7)/2
  float* Yp = Yc + (size_t)p * 16;
  float xx = x * x, yy = y * y, zz = z * z;
  Yp[0] = 1.f;
  Yp[1] = s3 * x;
  Yp[2] = s3 * y;
  Yp[3] = s3 * z;
  Yp[4] = s15 * x * y;
  Yp[5] = s15 * y * z;
  Yp[6] = 0.5f * s5 * (3.f * zz - 1.f);
  Yp[7] = s15 * x * z;
  Yp[8] = 0.5f * s15 * (xx - yy);
  Yp[9] = c70 * y * (3.f * xx - yy);
  Yp[10] = c105 * x * y * z;
  Yp[11] = c42 * y * (5.f * zz - 1.f);
  Yp[12] = c7 * z * (5.f * zz - 3.f);
  Yp[13] = c42 * x * (5.f * zz - 1.f);
  Yp[14] = 0.5f * c105 * z * (xx - yy);
  Yp[15] = c70 * x * (xx - 3.f * yy);
  float xr = rr * 0.2f;
  float xr2 = xr * xr, xr4 = xr2 * xr2;
  float xr5 = xr4 * xr, xr6 = xr5 * xr, xr7 = xr6 * xr;
  float poly = 1.f - 21.f * xr5 + 35.f * xr6 - 15.f * xr7;
  float pref = 0.632455532034f /* sqrt(2/5) */ * ir * poly;
  float* fp = fc + (size_t)p * 8;
  // sin(n*pi*xr) via recurrence: s_{n+1} = 2*cos(pi*xr)*s_n - s_{n-1}
  float s1 = sinf(PI_F * xr), c1 = cosf(PI_F * xr);
  float sm = 0.f, sp2 = s1;
  fp[0] = pref * s1;
#pragma unroll
  for (int nb = 2; nb <= 8; ++nb) {
    float sn = 2.f * c1 * sp2 - sm;
    fp[nb - 1] = pref * sn;
    sm = sp2;
    sp2 = sn;
  }
}

// ---------------------------------------------------------------- fused MLP
#define ATILE 128  // edges per block tile
#define SFS 132    // f32 fc row stride
#define XKS 80     // bf16 act row stride (16B-aligned frags)

// LDS pool:
//   sFc  f32 [8][132]      @0      (4224 B)
//   sW1  f32 [8][64]       @4224   (2048 B)
//   sXbf bf16 [128][80]    @6272   (20480 B)
//   sWB  bf16 8192         @26752  (16384 B)  -> total 43136 B, 3 blocks/CU
__global__ __launch_bounds__(512, 3) void mlp_all_k(
    const float* __restrict__ fc, const float* __restrict__ Wr1,
    const unsigned short* __restrict__ Wpack, const int* __restrict__ nact_p,
    unsigned short* __restrict__ Rbuf, int layer_base, int nlay,
    size_t rstride, int ecap) {
  __shared__ __attribute__((aligned(16))) char sPool[43136];
  float* sFc = (float*)sPool;
  float* sW1 = (float*)(sPool + 4224);
  unsigned short* sXbf = (unsigned short*)(sPool + 6272);
  unsigned short* sWB = (unsigned short*)(sPool + 26752);

  int nact = min(*nact_p, ecap);
  int bid = blockIdx.x;
  int layer = layer_base + (nlay == 2 ? (bid & 1) : 0);
  int t0 = (nlay == 2 ? (bid >> 1) : bid) * ATILE;
  if (t0 >= nact || nact == 0) return;
  unsigned short* Rout = Rbuf + (size_t)layer * rstride;
  const unsigned short* wp = Wpack + (size_t)layer * WPK_PER_LAYER;
  int tid = threadIdx.x;
  {
    const float* w1g = Wr1 + (size_t)layer * 512;
    if (tid < 128) ((float4*)sW1)[tid] = ((const float4*)w1g)[tid];
    for (int i = tid; i < ATILE * 8; i += 512) {
      int el = i >> 3, k = i & 7;
      int e = min(t0 + el, nact - 1);
      sFc[k * SFS + el] = fc[(size_t)e * 8 + k];
    }
    // W2f|W3f: 8192 ushorts = 1024 float4, pure copy
    for (int i = tid; i < 1024; i += 512)
      ((float4*)sWB)[i] = ((const float4*)wp)[i];
  }
  __syncthreads();

  int wid = tid >> 6, lane = tid & 63;
  // ---- L1 (f32, 4e4c mapping) -> bf16 acts
  {
    int stripe = wid >> 1;
    int ch = (wid & 1) * 32;
    int g = lane >> 3, q = lane & 7;
    int ebase = stripe * 32 + g * 4;
    int cbase = ch + q * 4;
    float a[4][4];
#pragma unroll
    for (int j = 0; j < 4; ++j)
#pragma unroll
      for (int i = 0; i < 4; ++i) a[j][i] = 0.f;
#pragma unroll
    for (int k = 0; k < 8; ++k) {
      float4 x = *(const float4*)&sFc[k * SFS + ebase];
      float4 w = *(const float4*)&sW1[k * 64 + cbase];
      float xs[4] = {x.x, x.y, x.z, x.w};
      float ws[4] = {w.x, w.y, w.z, w.w};
#pragma unroll
      for (int j = 0; j < 4; ++j)
#pragma unroll
        for (int i = 0; i < 4; ++i) a[j][i] += xs[j] * ws[i];
    }
#pragma unroll
    for (int j = 0; j < 4; ++j) {
      ushort4 v = {f2bf(silu_f(a[j][0])), f2bf(silu_f(a[j][1])),
                   f2bf(silu_f(a[j][2])), f2bf(silu_f(a[j][3]))};
      *(ushort4*)&sXbf[(ebase + j) * XKS + cbase] = v;
    }
  }
  __syncthreads();

  // ---- L2, L3 MFMA (wave-private 16-row band; no inter-wave barriers)
  int et = wid;
  int arow = et * 16 + (lane & 15);
  int kofs = (lane >> 4) * 8;
  int row0 = et * 16 + (lane >> 4) * 4;
#pragma unroll
  for (int ly = 0; ly < 2; ++ly) {
    const unsigned short* wb = sWB + ly * 4096;
    short8v a0 = *(const short8v*)&sXbf[arow * XKS + kofs];
    short8v a1 = *(const short8v*)&sXbf[arow * XKS + 32 + kofs];
    LDSFENCE();  // A-frags in regs before D overwrites the same rows
#pragma unroll
    for (int ct = 0; ct < 4; ++ct) {
      short8v b0 = *(const short8v*)&wb[((ct * 2 + 0) * 64 + lane) * 8];
      short8v b1 = *(const short8v*)&wb[((ct * 2 + 1) * 64 + lane) * 8];
      floatx4 acc = {0.f, 0.f, 0.f, 0.f};
      acc = __builtin_amdgcn_mfma_f32_16x16x32_bf16(a0, b0, acc, 0, 0, 0);
      acc = __builtin_amdgcn_mfma_f32_16x16x32_bf16(a1, b1, acc, 0, 0, 0);
      int col = ct * 16 + (lane & 15);
#pragma unroll
      for (int i2 = 0; i2 < 4; ++i2)
        sXbf[(row0 + i2) * XKS + col] = f2bf(silu_f(acc[i2]));
    }
    LDSFENCE();  // D-writes committed before next layer's A-reads
  }

  // ---- L4 MFMA over two 128-col W4 halves copied from the pack
  __syncthreads();  // all waves done reading sWB (W3)
  for (int i = tid; i < 1024; i += 512)
    ((float4*)sWB)[i] = ((const float4*)(wp + 8192))[i];
  __syncthreads();
  short8v a0 = *(const short8v*)&sXbf[arow * XKS + kofs];
  short8v a1 = *(const short8v*)&sXbf[arow * XKS + 32 + kofs];
#pragma unroll
  for (int half = 0; half < 2; ++half) {
#pragma unroll 4
    for (int ct = 0; ct < 8; ++ct) {
      short8v b0 = *(const short8v*)&sWB[((ct * 2 + 0) * 64 + lane) * 8];
      short8v b1 = *(const short8v*)&sWB[((ct * 2 + 1) * 64 + lane) * 8];
      floatx4 acc = {0.f, 0.f, 0.f, 0.f};
      acc = __builtin_amdgcn_mfma_f32_16x16x32_bf16(a0, b0, acc, 0, 0, 0);
      acc = __builtin_amdgcn_mfma_f32_16x16x32_bf16(a1, b1, acc, 0, 0, 0);
      int col = half * 128 + ct * 16 + (lane & 15);
#pragma unroll
      for (int i2 = 0; i2 < 4; ++i2) {
        int eg = t0 + row0 + i2;
        if (eg < nact) Rout[(size_t)eg * 256 + col] = f2bf(acc[i2]);
      }
    }
    if (half == 0) {
      __syncthreads();  // all reads of half-0 frags done
      for (int i = tid; i < 1024; i += 512)
        ((float4*)sWB)[i] = ((const float4*)(wp + 16384))[i];
      __syncthreads();
    }
  }
}

// ---------------------------------------------------------------- node layer
// Streams per-edge (R bf16, hs, Y) with 8-edge guarded load batches,
// accumulates acc[16], then node update (Wp from LDS) + per-node readout.
__global__ __launch_bounds__(512, 2) void gather_node_k(
    const float* __restrict__ h_in, float* __restrict__ h_out,
    const unsigned short* __restrict__ Rbuf, const float* __restrict__ Wsc,
    const float* __restrict__ Wp, const float* __restrict__ Wread,
    const float* __restrict__ Yc, const int* __restrict__ send,
    const int* __restrict__ off, const int* __restrict__ spec,
    float* __restrict__ eread, int N, int NE, int layer) {
  __shared__ __attribute__((aligned(16))) float sWp[4096];  // 16 KB
  __shared__ __attribute__((aligned(16))) float sVec[8][64];
  int tid = threadIdx.x;
  {
    const float* wp = Wp + (size_t)layer * 4096;
    for (int i = tid; i < 4096; i += 512) sWp[i] = wp[i];
  }
  __syncthreads();
  int wid = tid >> 6, lane = tid & 63;
  int n = blockIdx.x * 8 + wid;
  if (n >= N) return;

  int base = off[n];
  int deg = off[n + 1] - base;
  float acc[16];
#pragma unroll
  for (int i = 0; i < 16; ++i) acc[i] = 0.f;

  for (int b = 0; b < deg; b += 8) {
    int m = min(8, deg - b);
    int eu[8];
    float hs[8], r[8][4];
    // ---- load phase: up to 40 independent loads in flight (guarded,
    // wave-uniform j<m -> skipped entirely for absent edges)
#pragma unroll
    for (int j = 0; j < 8; ++j) {
      if (j < m) {
        int e = base + b + j;
        eu[j] = __builtin_amdgcn_readfirstlane(e);
        hs[j] = h_in[(size_t)send[eu[j]] * 64 + lane];
#pragma unroll
        for (int l = 0; l < 4; ++l)
          r[j][l] = bf2f(Rbuf[(size_t)eu[j] * 256 + l * 64 + lane]);
      }
    }
    // ---- compute phase
#pragma unroll
    for (int j = 0; j < 8; ++j) {
      if (j < m) {  // wave-uniform
        const float* yp = Yc + (size_t)eu[j] * 16;  // uniform -> s_loads
        float t0_ = hs[j] * r[j][0], t1_ = hs[j] * r[j][1];
        float t2_ = hs[j] * r[j][2], t3_ = hs[j] * r[j][3];
        acc[0] += yp[0] * t0_;
        acc[1] += yp[1] * t1_;   acc[2] += yp[2] * t1_;   acc[3] += yp[3] * t1_;
        acc[4] += yp[4] * t2_;   acc[5] += yp[5] * t2_;   acc[6] += yp[6] * t2_;
        acc[7] += yp[7] * t2_;   acc[8] += yp[8] * t2_;
        acc[9] += yp[9] * t3_;   acc[10] += yp[10] * t3_;
        acc[11] += yp[11] * t3_; acc[12] += yp[12] * t3_;
        acc[13] += yp[13] * t3_; acc[14] += yp[14] * t3_;
        acc[15] += yp[15] * t3_;
      }
    }
  }

  // node update: inv = A0 + sum_lm A^2   (A = acc / 16)
  float inv = acc[0] * 0.0625f;
#pragma unroll
  for (int i = 0; i < 16; ++i) {
    float a2 = acc[i] * 0.0625f;
    inv += a2 * a2;
  }
  float* sv = sVec[wid];
  sv[lane] = inv;
  LDSFENCE();
  int sp = spec[n];
  const float* wsc = Wsc + ((size_t)layer * NE + sp) * 4096;
  const float* hold = h_in + (size_t)n * 64;
  float hv = 0.f;
#pragma unroll 8
  for (int k = 0; k < 64; ++k) {
    hv += sv[k] * sWp[k * 64 + lane];
    hv += hold[k] * wsc[k * 64 + lane];
  }
  h_out[(size_t)n * 64 + lane] = hv;
  LDSFENCE();
  sv[lane] = hv;
  LDSFENCE();
  if (lane < 3) {
    const float* wr = Wread + (size_t)layer * 64 * 3;
    float s = 0.f;
#pragma unroll 8
    for (int d = 0; d < 64; ++d) s += sv[d] * wr[d * 3 + lane];
    if (layer == 0)
      eread[(size_t)n * 4 + lane] = s;   // first layer: store (no memset)
    else
      eread[(size_t)n * 4 + lane] += s;  // private to this wave: no atomic
  }
}

// ---------------------------------------------------------------- energy out
// One block per graph; batch is sorted -> binary-search the segment.
__global__ __launch_bounds__(256) void reduce_energy_k(
    const float* __restrict__ node_e0, const float* __restrict__ eread,
    const int* __restrict__ batch, float* __restrict__ out, int N, int G) {
  __shared__ float red[256 * 4];
  int g = blockIdx.x;
  int tid = threadIdx.x;
  int lo = 0, hi = N;
  while (lo < hi) {
    int mid = (lo + hi) >> 1;
    if (batch[mid] < g) lo = mid + 1; else hi = mid;
  }
  int start = lo;
  hi = N;
  while (lo < hi) {
    int mid = (lo + hi) >> 1;
    if (batch[mid] < g + 1) lo = mid + 1; else hi = mid;
  }
  int end = lo;
  float p0 = 0.f, p1 = 0.f, p2 = 0.f;
  for (int n = start + tid; n < end; n += 256) {
    float e0 = node_e0[n];
    p0 += e0 + eread[(size_t)n * 4 + 0];
    p1 += e0 + eread[(size_t)n * 4 + 1];
    p2 += e0 + eread[(size_t)n * 4 + 2];
  }
  red[tid * 4 + 0] = p0;
  red[tid * 4 + 1] = p1;
  red[tid * 4 + 2] = p2;
  __syncthreads();
  for (int s = 128; s > 0; s >>= 1) {
    if (tid < s) {
      red[tid * 4 + 0] += red[(tid + s) * 4 + 0];
      red[tid * 4 + 1] += red[(tid + s) * 4 + 1];
      red[tid * 4 + 2] += red[(tid + s) * 4 + 2];
    }
    __syncthreads();
  }
  if (tid < 3) out[g * 3 + tid] = red[tid];
}

// ---------------------------------------------------------------- host
extern "C" void kernel_launch(void* const* d_in, const int* in_sizes, int n_in,
                              void* d_out, int out_size, void* d_ws,
                              size_t ws_size, hipStream_t stream) {
  const float* pos = (const float*)d_in[0];
  const float* shifts = (const float*)d_in[1];
  const float* attrs = (const float*)d_in[2];
  const float* ae = (const float*)d_in[3];
  const float* Wemb = (const float*)d_in[4];
  const float* Wr1 = (const float*)d_in[5];
  const float* Wr2 = (const float*)d_in[6];
  const float* Wr3 = (const float*)d_in[7];
  const float* Wr4 = (const float*)d_in[8];
  const float* Wsc = (const float*)d_in[9];
  const float* Wp = (const float*)d_in[10];
  const float* Wrd = (const float*)d_in[11];
  const int* ei = (const int*)d_in[12];
  const int* batch = (const int*)d_in[13];

  int N = in_sizes[0] / 3;
  int E = in_sizes[12] / 2;
  int NE = in_sizes[3];
  int nlayer = in_sizes[5] / (8 * 64);
  int G = out_size / 3;

  // fixed overhead: h0/h1 + per-node arrays + Wpack + slack
  size_t fixed = (size_t)N * 64 * 4 * 2 + (size_t)N * 4 * 12 +
                 (size_t)nlayer * WPK_PER_LAYER * 2 + (1 << 20);
  size_t avail = ws_size > fixed ? ws_size - fixed : 0;
  // fused (2-layer bf16 Rbuf): 64+32+4 + 2*512 = 1124 B/edge; fallback 612
  int ecap2 = (int)(avail / 1124);
  bool fused = (nlayer == 2) && (ecap2 >= 50000);
  int ecap;
  if (fused) {
    ecap = ecap2 > ECAP_MAX ? ECAP_MAX : ecap2;
  } else {
    int ecap1 = (int)(avail / 612);
    ecap = ecap1 > ECAP_MAX ? ECAP_MAX : ecap1;
  }
  int nrl = fused ? nlayer : 1;  // Rbuf layer count
  size_t rstride = fused ? (size_t)ecap * 256 : 0;

  char* w = (char*)d_ws;
  auto alloc = [&](size_t bytes) {
    void* p = (void*)w;
    w += (bytes + 255) & ~(size_t)255;
    return p;
  };
  float* h0 = (float*)alloc((size_t)N * 64 * 4);
  float* h1 = (float*)alloc((size_t)N * 64 * 4);
  float* Yc = (float*)alloc((size_t)ecap * 16 * 4);
  float* fc = (float*)alloc((size_t)ecap * 8 * 4);
  unsigned short* Rbuf =
      (unsigned short*)alloc((size_t)ecap * 256 * 2 * nrl);
  unsigned short* Wpack =
      (unsigned short*)alloc((size_t)nlayer * WPK_PER_LAYER * 2);
  int* send = (int*)alloc((size_t)ecap * 4);
  int* off = (int*)alloc((size_t)(N + 1) * 4);
  int* deg = (int*)alloc((size_t)N * 4);
  int* cur = (int*)alloc((size_t)N * 4);
  int* spec = (int*)alloc((size_t)N * 4);
  float* node_e0 = (float*)alloc((size_t)N * 4);
  float* eread = (float*)alloc((size_t)N * 4 * 4);

  int nclr = (N + 255) / 256;
  int npk = (nlayer * WPK_PER_LAYER + 255) / 256;
  clear_pack_k<<<nclr + npk, 256, 0, stream>>>(deg, cur, N, Wr2, Wr3, Wr4,
                                               Wpack, nlayer, nclr);
  int nblk = (N + 3) / 4;
  int eblk = (E + 255) / 256;
  prep_k<<<nblk + eblk, 256, 0, stream>>>(attrs, ae, Wemb, h0, spec, node_e0,
                                          N, NE, pos, shifts, ei, deg, E,
                                          nblk);
  scan_deg_k<<<1, 1024, 0, stream>>>(deg, off, N);
  edge_fill_k<<<(E + 255) / 256, 256, 0, stream>>>(pos, shifts, ei, off, cur,
                                                   send, Yc, fc, E, ecap);
  const int* nact_p = off + N;
  int ntile = (E + ATILE - 1) / ATILE;
  float* hin = h0;
  float* hout = h1;
  if (fused) {
    // both layers' radial MLP in ONE dispatch (depends only on fc)
    mlp_all_k<<<2 * ntile, 512, 0, stream>>>(fc, Wr1, Wpack, nact_p, Rbuf, 0,
                                             2, rstride, ecap);
    for (int l = 0; l < nlayer; ++l) {
      gather_node_k<<<(N + 7) / 8, 512, 0, stream>>>(
          hin, hout, Rbuf + (size_t)l * rstride, Wsc, Wp, Wrd, Yc, send, off,
          spec, eread, N, NE, l);
      float* t = hin;
      hin = hout;
      hout = t;
    }
  } else {
    for (int l = 0; l < nlayer; ++l) {
      mlp_all_k<<<ntile, 512, 0, stream>>>(fc, Wr1, Wpack, nact_p, Rbuf, l, 1,
                                           0, ecap);
      gather_node_k<<<(N + 7) / 8, 512, 0, stream>>>(hin, hout, Rbuf, Wsc, Wp,
                                                     Wrd, Yc, send, off, spec,
                                                     eread, N, NE, l);
      float* t = hin;
      hin = hout;
      hout = t;
    }
  }
  reduce_energy_k<<<G, 256, 0, stream>>>(node_e0, eread, batch, (float*)d_out,
                                         N, G);
}

// Round 21
// 116.361 us; speedup vs baseline: 1.2180x; 1.2180x over previous
//
#include <hip/hip_runtime.h>
#include <math.h>
#include <stdint.h>

// EMACE forward. R21 = R19 (118.6 us best) + R20's clear/pack merge only.
// R20's 8-edge guarded gather batches REGRESSED (+23 us): guarded loads
// serialize under divergent control flow and (512,2) cut TLP. Reverted to
// R19's branchless 4-edge clamped batches at (512,3).

#define PI_F 3.14159265358979323846f
#define ECAP_MAX 72000       // active-edge capacity (expected ~46k)
#define WPK_PER_LAYER 24576  // 4096 (W2f) + 4096 (W3f) + 16384 (W4f)

__device__ __forceinline__ float silu_f(float x) { return x / (1.f + __expf(-x)); }

__device__ __forceinline__ unsigned short f2bf(float f) {
  unsigned int u = __float_as_uint(f);
  u = (u + 0x7FFFu + ((u >> 16) & 1u)) >> 16;  // round-to-nearest-even
  return (unsigned short)u;
}
__device__ __forceinline__ float bf2f(unsigned short h) {
  return __uint_as_float(((unsigned int)h) << 16);
}

typedef __attribute__((ext_vector_type(8))) short short8v;  // 8 bf16
typedef __attribute__((ext_vector_type(4))) float floatx4;  // 4 f32 acc

#define LDSFENCE() asm volatile("s_waitcnt lgkmcnt(0)" ::: "memory")

// B-fragment index for a [64k x NC] weight element (k, c) (HW-verified R17/18)
__device__ __forceinline__ int bfrag_idx(int k, int c) {
  return ((((c >> 4) * 2 + (k >> 5)) * 64) + (((k >> 3) & 3) * 16 + (c & 15))) * 8 +
         (k & 7);
}

// ------------------------------------------------- clear + weight pre-pack
__global__ void clear_pack_k(int* __restrict__ deg, int* __restrict__ cur,
                             int N, const float* __restrict__ Wr2,
                             const float* __restrict__ Wr3,
                             const float* __restrict__ Wr4,
                             unsigned short* __restrict__ Wpack, int nlayer,
                             int nclr) {
  int bid = blockIdx.x;
  if (bid < nclr) {
    int i = bid * 256 + threadIdx.x;
    if (i < N) {
      deg[i] = 0;
      cur[i] = 0;
    }
    return;
  }
  int i = (bid - nclr) * 256 + threadIdx.x;
  int total = nlayer * WPK_PER_LAYER;
  if (i >= total) return;
  int layer = i / WPK_PER_LAYER, r = i % WPK_PER_LAYER;
  unsigned short* dst = Wpack + (size_t)layer * WPK_PER_LAYER;
  if (r < 4096) {
    int k = r >> 6, c = r & 63;
    dst[bfrag_idx(k, c)] = f2bf(Wr2[(size_t)layer * 4096 + r]);
  } else if (r < 8192) {
    int q = r - 4096;
    int k = q >> 6, c = q & 63;
    dst[4096 + bfrag_idx(k, c)] = f2bf(Wr3[(size_t)layer * 4096 + q]);
  } else {
    int q = r - 8192;
    int k = q >> 8, c = q & 255;
    dst[8192 + (c >> 7) * 8192 + bfrag_idx(k, c & 127)] =
        f2bf(Wr4[(size_t)layer * 16384 + q]);
  }
}

// --------------------------------------------------- node init + edge count
__global__ void prep_k(const float* __restrict__ attrs,
                       const float* __restrict__ ae,
                       const float* __restrict__ Wemb, float* __restrict__ h0,
                       int* __restrict__ spec, float* __restrict__ node_e0,
                       int N, int NE, const float* __restrict__ pos,
                       const float* __restrict__ shifts,
                       const int* __restrict__ ei, int* __restrict__ deg,
                       int E, int nblk) {
  int bid = blockIdx.x;
  if (bid < nblk) {
    int n = bid * 4 + ((int)threadIdx.x >> 6);
    int lane = threadIdx.x & 63;
    if (n >= N) return;
    const float* a = attrs + (size_t)n * NE;
    int sp = 0;
    for (int e = 0; e < NE; ++e)
      if (a[e] > 0.5f) sp = e;
    h0[(size_t)n * 64 + lane] = Wemb[sp * 64 + lane];
    if (lane == 0) {
      spec[n] = sp;
      node_e0[n] = ae[sp];
    }
  } else {
    int e = (bid - nblk) * 256 + threadIdx.x;
    if (e >= E) return;
    int s = ei[e], r = ei[E + e];
    float dx = pos[r * 3 + 0] - pos[s * 3 + 0] + shifts[e * 3 + 0];
    float dy = pos[r * 3 + 1] - pos[s * 3 + 1] + shifts[e * 3 + 1];
    float dz = pos[r * 3 + 2] - pos[s * 3 + 2] + shifts[e * 3 + 2];
    float d2 = dx * dx + dy * dy + dz * dz;
    if (d2 < 25.0f) atomicAdd(&deg[r], 1);
  }
}

// ---------------------------------------------------------------- scan
__global__ void scan_deg_k(const int* __restrict__ deg, int* __restrict__ off,
                           int N) {
  __shared__ int sdat[1024];
  int tid = threadIdx.x;
  int chunk = (N + 1023) / 1024;
  int s0 = tid * chunk, s1 = min(s0 + chunk, N);
  int s = 0;
  for (int i = s0; i < s1; ++i) s += deg[i];
  sdat[tid] = s;
  __syncthreads();
  for (int d = 1; d < 1024; d <<= 1) {
    int v = (tid >= d) ? sdat[tid - d] : 0;
    __syncthreads();
    sdat[tid] += v;
    __syncthreads();
  }
  int run = sdat[tid] - s;  // exclusive prefix
  for (int i = s0; i < s1; ++i) {
    off[i] = run;
    run += deg[i];
  }
  if (tid == 1023) off[N] = sdat[1023];
}

// ---------------------------------------------------------------- edge pass 2
__global__ void edge_fill_k(const float* __restrict__ pos,
                            const float* __restrict__ shifts,
                            const int* __restrict__ ei,
                            const int* __restrict__ off, int* __restrict__ cur,
                            int* __restrict__ send, float* __restrict__ Yc,
                            float* __restrict__ fc, int E, int ecap) {
  int e = blockIdx.x * blockDim.x + threadIdx.x;
  if (e >= E) return;
  int s = ei[e], r = ei[E + e];
  float dx = pos[r * 3 + 0] - pos[s * 3 + 0] + shifts[e * 3 + 0];
  float dy = pos[r * 3 + 1] - pos[s * 3 + 1] + shifts[e * 3 + 1];
  float dz = pos[r * 3 + 2] - pos[s * 3 + 2] + shifts[e * 3 + 2];
  float rr = sqrtf(dx * dx + dy * dy + dz * dz + 1e-12f);
  if (rr >= 5.0f) return;  // inactive edge: cutoff=0 -> R=0 -> msg=0
  int p = off[r] + atomicAdd(&cur[r], 1);
  if (p >= ecap) return;  // statistically impossible; memory-safety guard
  send[p] = s;
  float ir = 1.f / rr;
  float x = dx * ir, y = dy * ir, z = dz * ir;
  const float s3 = 1.73205080757f, s5 = 2.23606797750f, s15 = 3.87298334621f;
  const float c70 = 2.09165006634f;   // sqrt(70)/4
  const float c105 = 10.2469507660f;  // sqrt(105)
  const float c42 = 1.62018517460f;   // sqrt(42)/4
  const float c7 = 1.32287565553f;    // sqrt(7)/2
  float* Yp = Yc + (size_t)p * 16;
  float xx = x * x, yy = y * y, zz = z * z;
  Yp[0] = 1.f;
  Yp[1] = s3 * x;
  Yp[2] = s3 * y;
  Yp[3] = s3 * z;
  Yp[4] = s15 * x * y;
  Yp[5] = s15 * y * z;
  Yp[6] = 0.5f * s5 * (3.f * zz - 1.f);
  Yp[7] = s15 * x * z;
  Yp[8] = 0.5f * s15 * (xx - yy);
  Yp[9] = c70 * y * (3.f * xx - yy);
  Yp[10] = c105 * x * y * z;
  Yp[11] = c42 * y * (5.f * zz - 1.f);
  Yp[12] = c7 * z * (5.f * zz - 3.f);
  Yp[13] = c42 * x * (5.f * zz - 1.f);
  Yp[14] = 0.5f * c105 * z * (xx - yy);
  Yp[15] = c70 * x * (xx - 3.f * yy);
  float xr = rr * 0.2f;
  float xr2 = xr * xr, xr4 = xr2 * xr2;
  float xr5 = xr4 * xr, xr6 = xr5 * xr, xr7 = xr6 * xr;
  float poly = 1.f - 21.f * xr5 + 35.f * xr6 - 15.f * xr7;
  float pref = 0.632455532034f /* sqrt(2/5) */ * ir * poly;
  float* fp = fc + (size_t)p * 8;
  // sin(n*pi*xr) via recurrence: s_{n+1} = 2*cos(pi*xr)*s_n - s_{n-1}
  float s1 = sinf(PI_F * xr), c1 = cosf(PI_F * xr);
  float sm = 0.f, sp2 = s1;
  fp[0] = pref * s1;
#pragma unroll
  for (int nb = 2; nb <= 8; ++nb) {
    float sn = 2.f * c1 * sp2 - sm;
    fp[nb - 1] = pref * sn;
    sm = sp2;
    sp2 = sn;
  }
}

// ---------------------------------------------------------------- fused MLP
#define ATILE 128  // edges per block tile
#define SFS 132    // f32 fc row stride
#define XKS 80     // bf16 act row stride (16B-aligned frags)

// LDS pool:
//   sFc  f32 [8][132]      @0      (4224 B)
//   sW1  f32 [8][64]       @4224   (2048 B)
//   sXbf bf16 [128][80]    @6272   (20480 B)
//   sWB  bf16 8192         @26752  (16384 B)  -> total 43136 B, 3 blocks/CU
__global__ __launch_bounds__(512, 3) void mlp_all_k(
    const float* __restrict__ fc, const float* __restrict__ Wr1,
    const unsigned short* __restrict__ Wpack, const int* __restrict__ nact_p,
    unsigned short* __restrict__ Rbuf, int layer_base, int nlay,
    size_t rstride, int ecap) {
  __shared__ __attribute__((aligned(16))) char sPool[43136];
  float* sFc = (float*)sPool;
  float* sW1 = (float*)(sPool + 4224);
  unsigned short* sXbf = (unsigned short*)(sPool + 6272);
  unsigned short* sWB = (unsigned short*)(sPool + 26752);

  int nact = min(*nact_p, ecap);
  int bid = blockIdx.x;
  int layer = layer_base + (nlay == 2 ? (bid & 1) : 0);
  int t0 = (nlay == 2 ? (bid >> 1) : bid) * ATILE;
  if (t0 >= nact || nact == 0) return;
  unsigned short* Rout = Rbuf + (size_t)layer * rstride;
  const unsigned short* wp = Wpack + (size_t)layer * WPK_PER_LAYER;
  int tid = threadIdx.x;
  {
    const float* w1g = Wr1 + (size_t)layer * 512;
    if (tid < 128) ((float4*)sW1)[tid] = ((const float4*)w1g)[tid];
    for (int i = tid; i < ATILE * 8; i += 512) {
      int el = i >> 3, k = i & 7;
      int e = min(t0 + el, nact - 1);
      sFc[k * SFS + el] = fc[(size_t)e * 8 + k];
    }
    // W2f|W3f: 8192 ushorts = 1024 float4, pure copy
    for (int i = tid; i < 1024; i += 512)
      ((float4*)sWB)[i] = ((const float4*)wp)[i];
  }
  __syncthreads();

  int wid = tid >> 6, lane = tid & 63;
  // ---- L1 (f32, 4e4c mapping) -> bf16 acts
  {
    int stripe = wid >> 1;
    int ch = (wid & 1) * 32;
    int g = lane >> 3, q = lane & 7;
    int ebase = stripe * 32 + g * 4;
    int cbase = ch + q * 4;
    float a[4][4];
#pragma unroll
    for (int j = 0; j < 4; ++j)
#pragma unroll
      for (int i = 0; i < 4; ++i) a[j][i] = 0.f;
#pragma unroll
    for (int k = 0; k < 8; ++k) {
      float4 x = *(const float4*)&sFc[k * SFS + ebase];
      float4 w = *(const float4*)&sW1[k * 64 + cbase];
      float xs[4] = {x.x, x.y, x.z, x.w};
      float ws[4] = {w.x, w.y, w.z, w.w};
#pragma unroll
      for (int j = 0; j < 4; ++j)
#pragma unroll
        for (int i = 0; i < 4; ++i) a[j][i] += xs[j] * ws[i];
    }
#pragma unroll
    for (int j = 0; j < 4; ++j) {
      ushort4 v = {f2bf(silu_f(a[j][0])), f2bf(silu_f(a[j][1])),
                   f2bf(silu_f(a[j][2])), f2bf(silu_f(a[j][3]))};
      *(ushort4*)&sXbf[(ebase + j) * XKS + cbase] = v;
    }
  }
  __syncthreads();

  // ---- L2, L3 MFMA (wave-private 16-row band; no inter-wave barriers)
  int et = wid;
  int arow = et * 16 + (lane & 15);
  int kofs = (lane >> 4) * 8;
  int row0 = et * 16 + (lane >> 4) * 4;
#pragma unroll
  for (int ly = 0; ly < 2; ++ly) {
    const unsigned short* wb = sWB + ly * 4096;
    short8v a0 = *(const short8v*)&sXbf[arow * XKS + kofs];
    short8v a1 = *(const short8v*)&sXbf[arow * XKS + 32 + kofs];
    LDSFENCE();  // A-frags in regs before D overwrites the same rows
#pragma unroll
    for (int ct = 0; ct < 4; ++ct) {
      short8v b0 = *(const short8v*)&wb[((ct * 2 + 0) * 64 + lane) * 8];
      short8v b1 = *(const short8v*)&wb[((ct * 2 + 1) * 64 + lane) * 8];
      floatx4 acc = {0.f, 0.f, 0.f, 0.f};
      acc = __builtin_amdgcn_mfma_f32_16x16x32_bf16(a0, b0, acc, 0, 0, 0);
      acc = __builtin_amdgcn_mfma_f32_16x16x32_bf16(a1, b1, acc, 0, 0, 0);
      int col = ct * 16 + (lane & 15);
#pragma unroll
      for (int i2 = 0; i2 < 4; ++i2)
        sXbf[(row0 + i2) * XKS + col] = f2bf(silu_f(acc[i2]));
    }
    LDSFENCE();  // D-writes committed before next layer's A-reads
  }

  // ---- L4 MFMA over two 128-col W4 halves copied from the pack
  __syncthreads();  // all waves done reading sWB (W3)
  for (int i = tid; i < 1024; i += 512)
    ((float4*)sWB)[i] = ((const float4*)(wp + 8192))[i];
  __syncthreads();
  short8v a0 = *(const short8v*)&sXbf[arow * XKS + kofs];
  short8v a1 = *(const short8v*)&sXbf[arow * XKS + 32 + kofs];
#pragma unroll
  for (int half = 0; half < 2; ++half) {
#pragma unroll 4
    for (int ct = 0; ct < 8; ++ct) {
      short8v b0 = *(const short8v*)&sWB[((ct * 2 + 0) * 64 + lane) * 8];
      short8v b1 = *(const short8v*)&sWB[((ct * 2 + 1) * 64 + lane) * 8];
      floatx4 acc = {0.f, 0.f, 0.f, 0.f};
      acc = __builtin_amdgcn_mfma_f32_16x16x32_bf16(a0, b0, acc, 0, 0, 0);
      acc = __builtin_amdgcn_mfma_f32_16x16x32_bf16(a1, b1, acc, 0, 0, 0);
      int col = half * 128 + ct * 16 + (lane & 15);
#pragma unroll
      for (int i2 = 0; i2 < 4; ++i2) {
        int eg = t0 + row0 + i2;
        if (eg < nact) Rout[(size_t)eg * 256 + col] = f2bf(acc[i2]);
      }
    }
    if (half == 0) {
      __syncthreads();  // all reads of half-0 frags done
      for (int i = tid; i < 1024; i += 512)
        ((float4*)sWB)[i] = ((const float4*)(wp + 16384))[i];
      __syncthreads();
    }
  }
}

// ---------------------------------------------------------------- node layer
// Streams per-edge (R bf16, hs, Y) with 4-edge branchless clamped batches,
// accumulates acc[16], then node update (Wp from LDS) + per-node readout.
__global__ __launch_bounds__(512, 3) void gather_node_k(
    const float* __restrict__ h_in, float* __restrict__ h_out,
    const unsigned short* __restrict__ Rbuf, const float* __restrict__ Wsc,
    const float* __restrict__ Wp, const float* __restrict__ Wread,
    const float* __restrict__ Yc, const int* __restrict__ send,
    const int* __restrict__ off, const int* __restrict__ spec,
    float* __restrict__ eread, int N, int NE, int layer) {
  __shared__ __attribute__((aligned(16))) float sWp[4096];  // 16 KB
  __shared__ __attribute__((aligned(16))) float sVec[8][64];
  int tid = threadIdx.x;
  {
    const float* wp = Wp + (size_t)layer * 4096;
    for (int i = tid; i < 4096; i += 512) sWp[i] = wp[i];
  }
  __syncthreads();
  int wid = tid >> 6, lane = tid & 63;
  int n = blockIdx.x * 8 + wid;
  if (n >= N) return;

  int base = off[n];
  int deg = off[n + 1] - base;
  float acc[16];
#pragma unroll
  for (int i = 0; i < 16; ++i) acc[i] = 0.f;

  for (int b = 0; b < deg; b += 4) {
    int m = min(4, deg - b);
    int eu[4];
    float hs[4], r[4][4];
    // ---- load phase: branchless clamped loads, all in flight
#pragma unroll
    for (int j = 0; j < 4; ++j) {
      int e = base + b + (j < m ? j : m - 1);
      eu[j] = __builtin_amdgcn_readfirstlane(e);
      hs[j] = h_in[(size_t)send[eu[j]] * 64 + lane];
#pragma unroll
      for (int l = 0; l < 4; ++l)
        r[j][l] = bf2f(Rbuf[(size_t)eu[j] * 256 + l * 64 + lane]);
    }
    // ---- compute phase
#pragma unroll
    for (int j = 0; j < 4; ++j) {
      if (j < m) {  // wave-uniform
        const float* yp = Yc + (size_t)eu[j] * 16;  // uniform -> s_loads
        float t0_ = hs[j] * r[j][0], t1_ = hs[j] * r[j][1];
        float t2_ = hs[j] * r[j][2], t3_ = hs[j] * r[j][3];
        acc[0] += yp[0] * t0_;
        acc[1] += yp[1] * t1_;   acc[2] += yp[2] * t1_;   acc[3] += yp[3] * t1_;
        acc[4] += yp[4] * t2_;   acc[5] += yp[5] * t2_;   acc[6] += yp[6] * t2_;
        acc[7] += yp[7] * t2_;   acc[8] += yp[8] * t2_;
        acc[9] += yp[9] * t3_;   acc[10] += yp[10] * t3_;
        acc[11] += yp[11] * t3_; acc[12] += yp[12] * t3_;
        acc[13] += yp[13] * t3_; acc[14] += yp[14] * t3_;
        acc[15] += yp[15] * t3_;
      }
    }
  }

  // node update: inv = A0 + sum_lm A^2   (A = acc / 16)
  float inv = acc[0] * 0.0625f;
#pragma unroll
  for (int i = 0; i < 16; ++i) {
    float a2 = acc[i] * 0.0625f;
    inv += a2 * a2;
  }
  float* sv = sVec[wid];
  sv[lane] = inv;
  LDSFENCE();
  int sp = spec[n];
  const float* wsc = Wsc + ((size_t)layer * NE + sp) * 4096;
  const float* hold = h_in + (size_t)n * 64;
  float hv = 0.f;
#pragma unroll 8
  for (int k = 0; k < 64; ++k) {
    hv += sv[k] * sWp[k * 64 + lane];
    hv += hold[k] * wsc[k * 64 + lane];
  }
  h_out[(size_t)n * 64 + lane] = hv;
  LDSFENCE();
  sv[lane] = hv;
  LDSFENCE();
  if (lane < 3) {
    const float* wr = Wread + (size_t)layer * 64 * 3;
    float s = 0.f;
#pragma unroll 8
    for (int d = 0; d < 64; ++d) s += sv[d] * wr[d * 3 + lane];
    if (layer == 0)
      eread[(size_t)n * 4 + lane] = s;   // first layer: store (no memset)
    else
      eread[(size_t)n * 4 + lane] += s;  // private to this wave: no atomic
  }
}

// ---------------------------------------------------------------- energy out
// One block per graph; batch is sorted -> binary-search the segment.
__global__ __launch_bounds__(256) void reduce_energy_k(
    const float* __restrict__ node_e0, const float* __restrict__ eread,
    const int* __restrict__ batch, float* __restrict__ out, int N, int G) {
  __shared__ float red[256 * 4];
  int g = blockIdx.x;
  int tid = threadIdx.x;
  int lo = 0, hi = N;
  while (lo < hi) {
    int mid = (lo + hi) >> 1;
    if (batch[mid] < g) lo = mid + 1; else hi = mid;
  }
  int start = lo;
  hi = N;
  while (lo < hi) {
    int mid = (lo + hi) >> 1;
    if (batch[mid] < g + 1) lo = mid + 1; else hi = mid;
  }
  int end = lo;
  float p0 = 0.f, p1 = 0.f, p2 = 0.f;
  for (int n = start + tid; n < end; n += 256) {
    float e0 = node_e0[n];
    p0 += e0 + eread[(size_t)n * 4 + 0];
    p1 += e0 + eread[(size_t)n * 4 + 1];
    p2 += e0 + eread[(size_t)n * 4 + 2];
  }
  red[tid * 4 + 0] = p0;
  red[tid * 4 + 1] = p1;
  red[tid * 4 + 2] = p2;
  __syncthreads();
  for (int s = 128; s > 0; s >>= 1) {
    if (tid < s) {
      red[tid * 4 + 0] += red[(tid + s) * 4 + 0];
      red[tid * 4 + 1] += red[(tid + s) * 4 + 1];
      red[tid * 4 + 2] += red[(tid + s) * 4 + 2];
    }
    __syncthreads();
  }
  if (tid < 3) out[g * 3 + tid] = red[tid];
}

// ---------------------------------------------------------------- host
extern "C" void kernel_launch(void* const* d_in, const int* in_sizes, int n_in,
                              void* d_out, int out_size, void* d_ws,
                              size_t ws_size, hipStream_t stream) {
  const float* pos = (const float*)d_in[0];
  const float* shifts = (const float*)d_in[1];
  const float* attrs = (const float*)d_in[2];
  const float* ae = (const float*)d_in[3];
  const float* Wemb = (const float*)d_in[4];
  const float* Wr1 = (const float*)d_in[5];
  const float* Wr2 = (const float*)d_in[6];
  const float* Wr3 = (const float*)d_in[7];
  const float* Wr4 = (const float*)d_in[8];
  const float* Wsc = (const float*)d_in[9];
  const float* Wp = (const float*)d_in[10];
  const float* Wrd = (const float*)d_in[11];
  const int* ei = (const int*)d_in[12];
  const int* batch = (const int*)d_in[13];

  int N = in_sizes[0] / 3;
  int E = in_sizes[12] / 2;
  int NE = in_sizes[3];
  int nlayer = in_sizes[5] / (8 * 64);
  int G = out_size / 3;

  // fixed overhead: h0/h1 + per-node arrays + Wpack + slack
  size_t fixed = (size_t)N * 64 * 4 * 2 + (size_t)N * 4 * 12 +
                 (size_t)nlayer * WPK_PER_LAYER * 2 + (1 << 20);
  size_t avail = ws_size > fixed ? ws_size - fixed : 0;
  // fused (2-layer bf16 Rbuf): 64+32+4 + 2*512 = 1124 B/edge; fallback 612
  int ecap2 = (int)(avail / 1124);
  bool fused = (nlayer == 2) && (ecap2 >= 50000);
  int ecap;
  if (fused) {
    ecap = ecap2 > ECAP_MAX ? ECAP_MAX : ecap2;
  } else {
    int ecap1 = (int)(avail / 612);
    ecap = ecap1 > ECAP_MAX ? ECAP_MAX : ecap1;
  }
  int nrl = fused ? nlayer : 1;  // Rbuf layer count
  size_t rstride = fused ? (size_t)ecap * 256 : 0;

  char* w = (char*)d_ws;
  auto alloc = [&](size_t bytes) {
    void* p = (void*)w;
    w += (bytes + 255) & ~(size_t)255;
    return p;
  };
  float* h0 = (float*)alloc((size_t)N * 64 * 4);
  float* h1 = (float*)alloc((size_t)N * 64 * 4);
  float* Yc = (float*)alloc((size_t)ecap * 16 * 4);
  float* fc = (float*)alloc((size_t)ecap * 8 * 4);
  unsigned short* Rbuf =
      (unsigned short*)alloc((size_t)ecap * 256 * 2 * nrl);
  unsigned short* Wpack =
      (unsigned short*)alloc((size_t)nlayer * WPK_PER_LAYER * 2);
  int* send = (int*)alloc((size_t)ecap * 4);
  int* off = (int*)alloc((size_t)(N + 1) * 4);
  int* deg = (int*)alloc((size_t)N * 4);
  int* cur = (int*)alloc((size_t)N * 4);
  int* spec = (int*)alloc((size_t)N * 4);
  float* node_e0 = (float*)alloc((size_t)N * 4);
  float* eread = (float*)alloc((size_t)N * 4 * 4);

  int nclr = (N + 255) / 256;
  int npk = (nlayer * WPK_PER_LAYER + 255) / 256;
  clear_pack_k<<<nclr + npk, 256, 0, stream>>>(deg, cur, N, Wr2, Wr3, Wr4,
                                               Wpack, nlayer, nclr);
  int nblk = (N + 3) / 4;
  int eblk = (E + 255) / 256;
  prep_k<<<nblk + eblk, 256, 0, stream>>>(attrs, ae, Wemb, h0, spec, node_e0,
                                          N, NE, pos, shifts, ei, deg, E,
                                          nblk);
  scan_deg_k<<<1, 1024, 0, stream>>>(deg, off, N);
  edge_fill_k<<<(E + 255) / 256, 256, 0, stream>>>(pos, shifts, ei, off, cur,
                                                   send, Yc, fc, E, ecap);
  const int* nact_p = off + N;
  int ntile = (E + ATILE - 1) / ATILE;
  float* hin = h0;
  float* hout = h1;
  if (fused) {
    // both layers' radial MLP in ONE dispatch (depends only on fc)
    mlp_all_k<<<2 * ntile, 512, 0, stream>>>(fc, Wr1, Wpack, nact_p, Rbuf, 0,
                                             2, rstride, ecap);
    for (int l = 0; l < nlayer; ++l) {
      gather_node_k<<<(N + 7) / 8, 512, 0, stream>>>(
          hin, hout, Rbuf + (size_t)l * rstride, Wsc, Wp, Wrd, Yc, send, off,
          spec, eread, N, NE, l);
      float* t = hin;
      hin = hout;
      hout = t;
    }
  } else {
    for (int l = 0; l < nlayer; ++l) {
      mlp_all_k<<<ntile, 512, 0, stream>>>(fc, Wr1, Wpack, nact_p, Rbuf, l, 1,
                                           0, ecap);
      gather_node_k<<<(N + 7) / 8, 512, 0, stream>>>(hin, hout, Rbuf, Wsc, Wp,
                                                     Wrd, Yc, send, off, spec,
                                                     eread, N, NE, l);
      float* t = hin;
      hin = hout;
      hout = t;
    }
  }
  reduce_energy_k<<<G, 256, 0, stream>>>(node_e0, eread, batch, (float*)d_out,
                                         N, G);
}